// Round 11
// baseline (137.094 us; speedup 1.0000x reference)
//
#include <hip/hip_runtime.h>
#include <hip/hip_bf16.h>
#include <stdint.h>

typedef __attribute__((ext_vector_type(8))) short  vshort8;
typedef __attribute__((ext_vector_type(4))) float  vfloat4;
typedef __attribute__((ext_vector_type(4))) int    vint4;

static constexpr int Bb   = 8;
static constexpr int Nn   = 1024;
static constexpr int FIN  = 512;
static constexpr int FOUT = 512;
static constexpr int Hh   = 8;
static constexpr int DH   = 64;
static constexpr int Mm   = Bb * Nn;          // 8192
static constexpr float LRELU_ALPHA = 0.2f;
static constexpr float LOG2E = 1.4426950408889634f;

__device__ __forceinline__ unsigned short f2bf(float f) {
  union { float f; uint32_t u; } c; c.f = f;
  uint32_t r = c.u + 0x7fffu + ((c.u >> 16) & 1u);   // RNE
  return (unsigned short)(r >> 16);
}
__device__ __forceinline__ float bf2f(unsigned short s) {
  union { uint32_t u; float f; } c; c.u = ((uint32_t)s) << 16; return c.f;
}

// ---------------- K0: fused prep: pack adj (ballot), cast x, transpose W ----
__global__ __launch_bounds__(256) void prep_kernel(const int* __restrict__ adj,
                                                   const float* __restrict__ x,
                                                   const float* __restrict__ W,
                                                   unsigned* __restrict__ packed,
                                                   short* __restrict__ xb,
                                                   short* __restrict__ Wt) {
  __shared__ float tile[64 * 65];
  const int bx = blockIdx.x, tid = threadIdx.x;
  if (bx < 2048) {                       // ---- pack_adj: wave per row, ballot
    const int rowid = bx * 4 + (tid >> 6);
    const int b = rowid >> 10, i = rowid & 1023;
    const int l = tid & 63;
    const int* src = adj + (size_t)rowid * Nn;
    unsigned myw = 0;
    #pragma unroll
    for (int k = 0; k < 16; ++k) {
      const int v = src[k * 64 + l];                 // coalesced 256B/wave
      const unsigned long long m = __ballot(v > 0);
      if (l == 2 * k)     myw = (unsigned)m;
      if (l == 2 * k + 1) myw = (unsigned)(m >> 32);
    }
    if (l < 32) packed[((size_t)b * 32 + l) * 1024 + i] = myw;
  } else if (bx < 3072) {                // ---- cast x -> bf16
    int i = ((bx - 2048) * 256 + tid) * 8;
    const int stride = 1024 * 256 * 8;
    for (; i < Mm * FIN; i += stride) {
      vfloat4 v0 = *(const vfloat4*)(x + i);
      vfloat4 v1 = *(const vfloat4*)(x + i + 4);
      vshort8 o;
      o[0] = (short)f2bf(v0[0]); o[1] = (short)f2bf(v0[1]);
      o[2] = (short)f2bf(v0[2]); o[3] = (short)f2bf(v0[3]);
      o[4] = (short)f2bf(v1[0]); o[5] = (short)f2bf(v1[1]);
      o[6] = (short)f2bf(v1[2]); o[7] = (short)f2bf(v1[3]);
      *(vshort8*)(xb + i) = o;
    }
  } else {                               // ---- W[k][n] -> Wt[n][k] bf16
    const int bxx = bx - 3072;
    const int n0 = (bxx & 7) * 64, k0 = (bxx >> 3) * 64;
    const int c = tid & 63, r4 = tid >> 6;
    #pragma unroll
    for (int rr = 0; rr < 64; rr += 4)
      tile[(rr + r4) * 65 + c] = W[(size_t)(k0 + rr + r4) * FOUT + n0 + c];
    __syncthreads();
    #pragma unroll
    for (int rr = 0; rr < 64; rr += 4)
      Wt[(size_t)(n0 + rr + r4) * FIN + k0 + c] = (short)f2bf(tile[c * 65 + rr + r4]);
  }
}

// ---------------- K2: gemm + fused scores epilogue --------------------------
// 64x64 tiles, depth-2 prefetch (3 LDS buffers), counted vmcnt: steady state
// keeps 2 tiles (8 loads/thread-wave) in flight; never drains mid-loop.
__device__ __forceinline__ void stage_ab(const short* __restrict__ A,
                                         const short* __restrict__ Bt,
                                         short* as, short* bs,
                                         int m0, int n0, int kt, int tid) {
  #pragma unroll
  for (int p = 0; p < 2; ++p) {
    const int idxS = p * 2048 + tid * 8;           // linear LDS dest (shorts)
    const int row  = idxS >> 6;
    const int cs   = (idxS & 63) * 2;              // dest byte col
    const int cd   = cs ^ ((row & 7) << 4);        // inverse-swizzled src col
    __builtin_amdgcn_global_load_lds(
        (const __attribute__((address_space(1))) unsigned int*)(A + (size_t)(m0 + row) * FIN + kt + (cd >> 1)),
        (__attribute__((address_space(3))) unsigned int*)(as + idxS), 16, 0, 0);
    __builtin_amdgcn_global_load_lds(
        (const __attribute__((address_space(1))) unsigned int*)(Bt + (size_t)(n0 + row) * FIN + kt + (cd >> 1)),
        (__attribute__((address_space(3))) unsigned int*)(bs + idxS), 16, 0, 0);
  }
}

__global__ __launch_bounds__(256, 3) void gemm_t_kernel(const short* __restrict__ A,
                                                        const short* __restrict__ Bt,
                                                        const float* __restrict__ bias,
                                                        const float* __restrict__ att,
                                                        short* __restrict__ hbt,
                                                        float* __restrict__ ssrc,
                                                        float* __restrict__ sdst) {
  __shared__ short As[3][4096];
  __shared__ short Bs[3][4096];
  const int tid = threadIdx.x;
  const int w = tid >> 6, l = tid & 63;
  const int lrow = l & 15, lk = l >> 4;
  const int m0 = blockIdx.x * 64, n0 = blockIdx.y * 64;
  vfloat4 acc[4] = {};
  stage_ab(A, Bt, As[0], Bs[0], m0, n0, 0, tid);
  stage_ab(A, Bt, As[1], Bs[1], m0, n0, 64, tid);
  #pragma unroll
  for (int ktt = 0; ktt < 8; ++ktt) {
    if (ktt < 6) {
      stage_ab(A, Bt, As[(ktt + 2) % 3], Bs[(ktt + 2) % 3], m0, n0, (ktt + 2) * 64, tid);
      asm volatile("s_waitcnt vmcnt(8)" ::: "memory");   // 2 newer tiles in flight
    } else if (ktt == 6) {
      asm volatile("s_waitcnt vmcnt(4)" ::: "memory");
    } else {
      asm volatile("s_waitcnt vmcnt(0)" ::: "memory");
    }
    asm volatile("s_barrier" ::: "memory");
    const int cb = ktt % 3;
    #pragma unroll
    for (int ks = 0; ks < 2; ++ks) {
      const int mrow = w * 16 + lrow;
      const int gc   = ks * 64 + lk * 16;            // wanted byte col
      vshort8 bf = *(const vshort8*)((const char*)As[cb] + mrow * 128 + (gc ^ ((mrow & 7) << 4)));
      #pragma unroll
      for (int i = 0; i < 4; ++i) {
        const int frow = i * 16 + lrow;
        vshort8 af = *(const vshort8*)((const char*)Bs[cb] + frow * 128 + (gc ^ ((frow & 7) << 4)));
        acc[i] = __builtin_amdgcn_mfma_f32_16x16x32_bf16(af, bf, acc[i], 0, 0, 0);
      }
    }
    asm volatile("s_barrier" ::: "memory");   // all waves done reading buf cb
  }
  // epilogue: hbt write + fused s_src/s_dst (n0-tile == one head)
  const int hh = n0 >> 6;
  const float* a_src = att + hh * 2 * DH;
  const float* a_dst = a_src + DH;
  const int mg = m0 + w * 16 + lrow;
  const int b = mg >> 10, n = mg & 1023;
  float ps = 0.f, pd = 0.f;
  #pragma unroll
  for (int i = 0; i < 4; ++i) {
    const int fbase = n0 + i * 16 + lk * 4;
    const vfloat4 bv = *(const vfloat4*)(bias + fbase);
    #pragma unroll
    for (int r = 0; r < 4; ++r) {
      const int fl = i * 16 + lk * 4 + r;            // fout-local in [0,64)
      const float hv = acc[i][r] + bv[r];
      ps += hv * a_src[fl];
      pd += hv * a_dst[fl];
      hbt[((size_t)(b * Hh + hh) * DH + fl) * Nn + n] = (short)f2bf(hv);
    }
  }
  ps += __shfl_xor(ps, 16); ps += __shfl_xor(ps, 32);
  pd += __shfl_xor(pd, 16); pd += __shfl_xor(pd, 32);
  if (l < 16) {                                      // lk==0 lane writes
    ssrc[(size_t)(b * Hh + hh) * Nn + n] = ps * LOG2E;
    sdst[(size_t)(b * Hh + hh) * Nn + n] = pd * LOG2E;
  }
}

// ---------------- K4: fused attention, depth-2 pipelined V staging ----------
__device__ __forceinline__ void stage_vb(const short* __restrict__ vbbase,
                                         short* lds_buf, int iw, int l, int jt) {
  #pragma unroll
  for (int k = 0; k < 4; ++k) {
    const int d  = iw * 16 + k * 4 + (l >> 4);
    const int cs = (l & 15) * 16;                  // stored byte offset in row
    const int cd = cs ^ ((d & 7) << 4);            // inverse-swizzled data offset
    const int j  = jt + (cd >> 1);
    __builtin_amdgcn_global_load_lds(
        (const __attribute__((address_space(1))) unsigned int*)(vbbase + (size_t)d * Nn + j),
        (__attribute__((address_space(3))) unsigned int*)(lds_buf + iw * 2048 + k * 512),
        16, 0, 0);
  }
}

__global__ __launch_bounds__(256, 3) void attn_kernel(const unsigned* __restrict__ packed,
                                                      const float* __restrict__ ssrc,
                                                      const float* __restrict__ sdst,
                                                      const short* __restrict__ hbt,
                                                      float* __restrict__ out) {
  __shared__ short vbl[3][8192];     // 3 x 16 KB: [64 d][128 j] bf16, swizzled
  __shared__ float slds[1024];       // whole ssrc row for (b,h), pre-scaled
  const int it = blockIdx.x, h = blockIdx.y, b = blockIdx.z;
  const int tid = threadIdx.x;
  const int iw = tid >> 6, l = tid & 63;
  const int lrow = l & 15, lk = l >> 4;
  const int i = it * 64 + iw * 16 + lrow;          // query row owned by this lane
  const float sdi = sdst[(size_t)(b * Hh + h) * Nn + i];
  const float* ssp = ssrc + (size_t)(b * Hh + h) * Nn;
  const short* vbbase = hbt + (size_t)(b * Hh + h) * DH * Nn;
  const unsigned* ap = packed + (size_t)b * 32 * 1024 + i;   // word w at ap[w*1024]

  // prologue: ssrc row (1 gll) + tiles 0,1 (each 4 gll + 4 adj loads)
  __builtin_amdgcn_global_load_lds(
      (const __attribute__((address_space(1))) unsigned int*)(ssp + iw * 256 + l * 4),
      (__attribute__((address_space(3))) unsigned int*)(slds + iw * 256),
      16, 0, 0);
  vint4 aq[3];
  stage_vb(vbbase, vbl[0], iw, l, 0);
  #pragma unroll
  for (int s = 0; s < 4; ++s) aq[0][s] = (int)ap[s * 1024];
  stage_vb(vbbase, vbl[1], iw, l, 128);
  #pragma unroll
  for (int s = 0; s < 4; ++s) aq[1][s] = (int)ap[(4 + s) * 1024];

  vshort8 ones;
  #pragma unroll
  for (int e = 0; e < 8; ++e) ones[e] = (short)0x3F80;   // bf16 1.0
  vfloat4 acc[4] = {};
  vfloat4 accd = {};

  #pragma unroll
  for (int t = 0; t < 8; ++t) {
    if (t < 6) {
      stage_vb(vbbase, vbl[(t + 2) % 3], iw, l, (t + 2) * 128);
      #pragma unroll
      for (int s = 0; s < 4; ++s) aq[(t + 2) % 3][s] = (int)ap[((t + 2) * 4 + s) * 1024];
      asm volatile("s_waitcnt vmcnt(16)" ::: "memory");   // 2 newer tiles in flight
    } else if (t == 6) {
      asm volatile("s_waitcnt vmcnt(8)" ::: "memory");
    } else {
      asm volatile("s_waitcnt vmcnt(0)" ::: "memory");
    }
    asm volatile("s_barrier" ::: "memory");

    const char* vc = (const char*)vbl[t % 3];
    const char* sc = (const char*)slds + t * 512;
    const vint4 acu = aq[t % 3];
    #pragma unroll
    for (int s = 0; s < 4; ++s) {
      const vfloat4 s0 = *(const vfloat4*)(sc + s * 128 + lk * 32);
      const vfloat4 s1 = *(const vfloat4*)(sc + s * 128 + lk * 32 + 16);
      const unsigned u = ((unsigned)acu[s]) >> (lk * 8);
      vshort8 af;
      #pragma unroll
      for (int e = 0; e < 4; ++e) {
        float tv = sdi + s0[e];
        tv = fmaxf(tv, LRELU_ALPHA * tv);                    // leaky_relu (log2 domain)
        const float pe = ((u >> e) & 1u) ? __builtin_amdgcn_exp2f(tv) : 0.f;
        af[e] = (short)__bfloat16_as_ushort(__float2bfloat16(pe));
      }
      #pragma unroll
      for (int e = 0; e < 4; ++e) {
        float tv = sdi + s1[e];
        tv = fmaxf(tv, LRELU_ALPHA * tv);
        const float pe = ((u >> (4 + e)) & 1u) ? __builtin_amdgcn_exp2f(tv) : 0.f;
        af[4 + e] = (short)__bfloat16_as_ushort(__float2bfloat16(pe));
      }
      const int cbase = (s * 64 + lk * 16) ^ ((lrow & 7) << 4);  // swizzled read
      vshort8 f0 = *(const vshort8*)(vc + (0 * 16 + lrow) * 256 + cbase);
      vshort8 f1 = *(const vshort8*)(vc + (1 * 16 + lrow) * 256 + cbase);
      vshort8 f2 = *(const vshort8*)(vc + (2 * 16 + lrow) * 256 + cbase);
      vshort8 f3 = *(const vshort8*)(vc + (3 * 16 + lrow) * 256 + cbase);
      acc[0] = __builtin_amdgcn_mfma_f32_16x16x32_bf16(af, f0, acc[0], 0, 0, 0);
      acc[1] = __builtin_amdgcn_mfma_f32_16x16x32_bf16(af, f1, acc[1], 0, 0, 0);
      acc[2] = __builtin_amdgcn_mfma_f32_16x16x32_bf16(af, f2, acc[2], 0, 0, 0);
      acc[3] = __builtin_amdgcn_mfma_f32_16x16x32_bf16(af, f3, acc[3], 0, 0, 0);
      accd   = __builtin_amdgcn_mfma_f32_16x16x32_bf16(af, ones, accd, 0, 0, 0);
    }
    asm volatile("s_barrier" ::: "memory");   // all waves done reading buf t%3
  }

  #pragma unroll
  for (int r = 0; r < 4; ++r) {
    const int lr = lk * 4 + r;                       // D-layout local row
    const float inv = 1.0f / accd[r];                // row-sum lives on this lane
    const int row = it * 64 + iw * 16 + lr;
    #pragma unroll
    for (int df = 0; df < 4; ++df) {
      float v = acc[df][r] * inv;
      v = v > 0.f ? v : expm1f(v);                   // ELU (alpha=1)
      out[((size_t)(b * Nn + row)) * FOUT + h * DH + df * 16 + lrow] = v;
    }
  }
}

extern "C" void kernel_launch(void* const* d_in, const int* in_sizes, int n_in,
                              void* d_out, int out_size, void* d_ws, size_t ws_size,
                              hipStream_t stream) {
  const float* x   = (const float*)d_in[0];
  const int*   adj = (const int*)d_in[1];
  const float* W   = (const float*)d_in[2];
  const float* Wb  = (const float*)d_in[3];
  const float* att = (const float*)d_in[4];
  float* out = (float*)d_out;

  // Scratch plan:
  //   d_out (16 MB, fully overwritten by attn_kernel at the end):
  //     [0, 8 MB)    xb = bf16 x (dead after gemm); [8, 8.5 MB) Wt (dead after gemm)
  //   d_ws (9.5 MB used):
  //     [0, 8 MB)    hbt = (x@W+b)^T as [b][h][d][n] bf16
  //     [8, 8.5 MB)  ssrc, sdst (f32, pre-scaled by log2e)
  //     [8.5,9.5 MB) packed adj bitmask, transposed [b][word][i]
  short* xb  = (short*)d_out;
  short* Wt  = xb + (size_t)Mm * FIN;
  short* hbt = (short*)d_ws;
  float* ssrc = (float*)(hbt + (size_t)Bb * Hh * DH * Nn);
  float* sdst = ssrc + (size_t)Bb * Hh * Nn;
  unsigned* packed = (unsigned*)(sdst + (size_t)Bb * Hh * Nn);

  prep_kernel<<<3136, 256, 0, stream>>>(adj, x, W, packed, xb, Wt);
  gemm_t_kernel<<<dim3(Mm / 64, FOUT / 64), 256, 0, stream>>>(xb, Wt, Wb, att, hbt, ssrc, sdst);
  attn_kernel<<<dim3(Nn / 64, Hh, Bb), 256, 0, stream>>>(packed, ssrc, sdst, hbt, out);
}